// Round 4
// baseline (989.203 us; speedup 1.0000x reference)
//
#include <hip/hip_runtime.h>
#include <math.h>

#define BATCH  128
#define NENT   256
#define INDIM  256
#define HID    512
#define NHEAD  8
#define NAGENT 64
#define SCALE  0.04419417382415922f   // 1/sqrt(512)

typedef unsigned short u16;
typedef unsigned int   u32;

typedef __bf16 bf16x8  __attribute__((ext_vector_type(8)));
typedef float  floatx4 __attribute__((ext_vector_type(4)));
typedef u32    u32x4   __attribute__((ext_vector_type(4)));
typedef u32    u32x2   __attribute__((ext_vector_type(2)));

union Frag {
    u32x4 s;
    struct { u32x2 lo, hi; } p;
    bf16x8 v;
};

__device__ __forceinline__ u16 f2bf(float x) {
    u32 u = __float_as_uint(x);
    return (u16)((u + 0x7FFFu + ((u >> 16) & 1u)) >> 16);
}
__device__ __forceinline__ float bf2f(u16 b) {
    return __uint_as_float(((u32)b) << 16);
}
__device__ __forceinline__ void split4(const float4& r, ushort4& hh, ushort4& hl) {
    hh.x = f2bf(r.x); hl.x = f2bf(r.x - bf2f(hh.x));
    hh.y = f2bf(r.y); hl.y = f2bf(r.y - bf2f(hh.y));
    hh.z = f2bf(r.z); hl.z = f2bf(r.z - bf2f(hh.z));
    hh.w = f2bf(r.w); hl.w = f2bf(r.w - bf2f(hh.w));
}

// -----------------------------------------------------------------------------
// K0: Wt[d][k] = split(W_enc[k][d])  (transpose + bf16 hi/lo), 512x256
// -----------------------------------------------------------------------------
__global__ __launch_bounds__(256) void wenc_t_kernel(const float* __restrict__ W,
                                                     u16* __restrict__ Wt_h,
                                                     u16* __restrict__ Wt_l) {
    __shared__ float tile[64][68];
    const int bid = blockIdx.x;          // 4 k-tiles x 8 d-tiles
    const int k0 = (bid & 3) * 64;
    const int d0 = (bid >> 2) * 64;
    const int t = threadIdx.x;
    const int ki = t >> 2, dc = (t & 3) * 16;
    #pragma unroll
    for (int c = 0; c < 4; ++c)
        *(float4*)&tile[ki][dc + c * 4] =
            *(const float4*)(W + (size_t)(k0 + ki) * HID + d0 + dc + c * 4);
    __syncthreads();
    const int dr = t >> 2, kc = (t & 3) * 16;
    #pragma unroll
    for (int c = 0; c < 4; ++c) {
        float4 v = make_float4(tile[kc + c * 4 + 0][dr], tile[kc + c * 4 + 1][dr],
                               tile[kc + c * 4 + 2][dr], tile[kc + c * 4 + 3][dr]);
        ushort4 hh, hl; split4(v, hh, hl);
        size_t o = (size_t)(d0 + dr) * INDIM + k0 + kc + c * 4;
        *(ushort4*)(Wt_h + o) = hh;
        *(ushort4*)(Wt_l + o) = hl;
    }
}

// -----------------------------------------------------------------------------
// K1: h = leaky_relu(x) @ W_enc + b_enc via split-bf16 3-pass MFMA.
// -----------------------------------------------------------------------------
__global__ __launch_bounds__(256) void enc_kernel(const float* __restrict__ x,
                                                  const u16* __restrict__ Wt_h,
                                                  const u16* __restrict__ Wt_l,
                                                  const float* __restrict__ bias,
                                                  u16* __restrict__ h_h,
                                                  u16* __restrict__ h_l) {
    __shared__ u16 Ah[32][264];
    __shared__ u16 Al[32][264];
    const int r0 = blockIdx.x * 32;
    const int t  = threadIdx.x;
    {
        const int row = t >> 3;
        const float* xr = x + (size_t)(r0 + row) * INDIM;
        #pragma unroll
        for (int j = 0; j < 8; ++j) {
            const int k0 = ((t & 7) + j * 8) * 4;
            float4 v = *(const float4*)(xr + k0);
            v.x = v.x > 0.f ? v.x : 0.01f * v.x;
            v.y = v.y > 0.f ? v.y : 0.01f * v.y;
            v.z = v.z > 0.f ? v.z : 0.01f * v.z;
            v.w = v.w > 0.f ? v.w : 0.01f * v.w;
            ushort4 hh, hl; split4(v, hh, hl);
            *(ushort4*)&Ah[row][k0] = hh;
            *(ushort4*)&Al[row][k0] = hl;
        }
    }
    __syncthreads();

    const int wid = t >> 6, lane = t & 63, l15 = lane & 15, quad = lane >> 4;
    const int mbase = (wid & 1) * 16;
    const int nbase = (wid >> 1) * 256;
    const floatx4 z4 = {0.f, 0.f, 0.f, 0.f};
    floatx4 acc[16];
    #pragma unroll
    for (int i = 0; i < 16; ++i) acc[i] = z4;

    for (int ks = 0; ks < 8; ++ks) {
        const int k = ks * 32 + quad * 8;
        Frag Afh, Afl;
        Afh.s = *(const u32x4*)&Ah[mbase + l15][k];
        Afl.s = *(const u32x4*)&Al[mbase + l15][k];
        #pragma unroll
        for (int nt = 0; nt < 16; ++nt) {
            const int d = nbase + nt * 16 + l15;
            Frag Bh, Bl;
            Bh.s = *(const u32x4*)(Wt_h + (size_t)d * INDIM + k);
            Bl.s = *(const u32x4*)(Wt_l + (size_t)d * INDIM + k);
            floatx4 c = acc[nt];
            c = __builtin_amdgcn_mfma_f32_16x16x32_bf16(Afh.v, Bh.v, c, 0, 0, 0);
            c = __builtin_amdgcn_mfma_f32_16x16x32_bf16(Afh.v, Bl.v, c, 0, 0, 0);
            c = __builtin_amdgcn_mfma_f32_16x16x32_bf16(Afl.v, Bh.v, c, 0, 0, 0);
            acc[nt] = c;
        }
    }
    #pragma unroll
    for (int nt = 0; nt < 16; ++nt) {
        const int d = nbase + nt * 16 + l15;
        const float bv = bias[d];
        #pragma unroll
        for (int r = 0; r < 4; ++r) {
            const float v = acc[nt][r] + bv;
            const u16 hi = f2bf(v);
            const u16 lo = f2bf(v - bf2f(hi));
            const size_t o = (size_t)(r0 + mbase + quad * 4 + r) * HID + d;
            h_h[o] = hi;
            h_l[o] = lo;
        }
    }
}

// -----------------------------------------------------------------------------
// K1b: hT[b][d][e] = h_h[b*256+e][d]  (64x64 u16 tile transpose)
// -----------------------------------------------------------------------------
__global__ __launch_bounds__(256) void ht_kernel(const u16* __restrict__ h_h,
                                                 u16* __restrict__ hT) {
    __shared__ u16 tile[64][72];
    const int bid = blockIdx.x;               // 8 dt x 4 et x 128 b
    const int dt = bid & 7;
    const int et = (bid >> 3) & 3;
    const int b  = bid >> 5;
    const int t  = threadIdx.x;
    const int r  = t >> 2, cs = (t & 3) * 16;
    const u16* src = h_h + (size_t)(b * 256 + et * 64 + r) * HID + dt * 64 + cs;
    *(ushort4*)&tile[r][cs + 0]  = *(const ushort4*)(src + 0);
    *(ushort4*)&tile[r][cs + 4]  = *(const ushort4*)(src + 4);
    *(ushort4*)&tile[r][cs + 8]  = *(const ushort4*)(src + 8);
    *(ushort4*)&tile[r][cs + 12] = *(const ushort4*)(src + 12);
    __syncthreads();
    const int d = t >> 2, es = (t & 3) * 16;
    u16* dst = hT + (size_t)b * 131072 + (size_t)(dt * 64 + d) * 256 + et * 64 + es;
    #pragma unroll
    for (int c = 0; c < 4; ++c) {
        ushort4 v = make_ushort4(tile[es + c * 4 + 0][d], tile[es + c * 4 + 1][d],
                                 tile[es + c * 4 + 2][d], tile[es + c * 4 + 3][d]);
        *(ushort4*)(dst + c * 4) = v;
    }
}

// -----------------------------------------------------------------------------
// K2: Mt[n][j][i] = SCALE * dot(WQ[n][i,:], WK[n][j,:]) via split MFMA.
// -----------------------------------------------------------------------------
__global__ __launch_bounds__(256) void wqk_kernel(const float* __restrict__ WQ,
                                                  const float* __restrict__ WK,
                                                  u16* __restrict__ Mt_h,
                                                  u16* __restrict__ Mt_l) {
    __shared__ u16 Ah[64][72], Al[64][72], Bh[64][72], Bl[64][72];
    const int bid = blockIdx.x;
    const int jt = (bid & 7) * 64;
    const int it = ((bid >> 3) & 7) * 64;
    const int n  = bid >> 6;
    const float* qp = WQ + (size_t)n * 262144;
    const float* kp = WK + (size_t)n * 262144;
    const int t = threadIdx.x;
    const int wid = t >> 6, lane = t & 63, l15 = lane & 15, quad = lane >> 4;
    const int srow = t >> 2, sc = (t & 3) * 16;

    const floatx4 z4 = {0.f, 0.f, 0.f, 0.f};
    floatx4 acc[4];
    #pragma unroll
    for (int i = 0; i < 4; ++i) acc[i] = z4;

    for (int kc = 0; kc < HID; kc += 64) {
        #pragma unroll
        for (int f = 0; f < 4; ++f) {
            float4 va = *(const float4*)(kp + (size_t)(jt + srow) * HID + kc + sc + f * 4);
            ushort4 hh, hl; split4(va, hh, hl);
            *(ushort4*)&Ah[srow][sc + f * 4] = hh;
            *(ushort4*)&Al[srow][sc + f * 4] = hl;
            float4 vb = *(const float4*)(qp + (size_t)(it + srow) * HID + kc + sc + f * 4);
            split4(vb, hh, hl);
            *(ushort4*)&Bh[srow][sc + f * 4] = hh;
            *(ushort4*)&Bl[srow][sc + f * 4] = hl;
        }
        __syncthreads();
        #pragma unroll
        for (int ks = 0; ks < 2; ++ks) {
            const int k = ks * 32 + quad * 8;
            Frag Afh, Afl;
            Afh.s = *(const u32x4*)&Ah[wid * 16 + l15][k];
            Afl.s = *(const u32x4*)&Al[wid * 16 + l15][k];
            #pragma unroll
            for (int nt = 0; nt < 4; ++nt) {
                Frag Bfh, Bfl;
                Bfh.s = *(const u32x4*)&Bh[nt * 16 + l15][k];
                Bfl.s = *(const u32x4*)&Bl[nt * 16 + l15][k];
                floatx4 c = acc[nt];
                c = __builtin_amdgcn_mfma_f32_16x16x32_bf16(Afh.v, Bfh.v, c, 0, 0, 0);
                c = __builtin_amdgcn_mfma_f32_16x16x32_bf16(Afh.v, Bfl.v, c, 0, 0, 0);
                c = __builtin_amdgcn_mfma_f32_16x16x32_bf16(Afl.v, Bfh.v, c, 0, 0, 0);
                acc[nt] = c;
            }
        }
        __syncthreads();
    }
    #pragma unroll
    for (int nt = 0; nt < 4; ++nt)
        #pragma unroll
        for (int r = 0; r < 4; ++r) {
            const float v = acc[nt][r] * SCALE;
            const u16 hi = f2bf(v);
            const u16 lo = f2bf(v - bf2f(hi));
            const int j = jt + wid * 16 + quad * 4 + r;
            const int i = it + nt * 16 + l15;
            const size_t o = (size_t)n * 262144 + (size_t)j * HID + i;
            Mt_h[o] = hi;
            Mt_l[o] = lo;
        }
}

// -----------------------------------------------------------------------------
// K3: WVt[n][dout][din] = bf16(WV[n][din][dout])
// -----------------------------------------------------------------------------
__global__ __launch_bounds__(256) void wvt_kernel(const float* __restrict__ WV,
                                                  u16* __restrict__ WVt) {
    __shared__ float tile[64][68];
    const int bid = blockIdx.x;
    const int i0 = (bid & 7) * 64;
    const int o0 = ((bid >> 3) & 7) * 64;
    const int n  = bid >> 6;
    const float* src = WV + (size_t)n * 262144;
    const int t  = threadIdx.x;
    const int di = t >> 2;
    const int dc = (t & 3) * 16;
    #pragma unroll
    for (int c = 0; c < 4; ++c)
        *(float4*)&tile[di][dc + c * 4] =
            *(const float4*)(src + (size_t)(i0 + di) * HID + o0 + dc + c * 4);
    __syncthreads();
    const int dr = t >> 2;
    const int ic = (t & 3) * 16;
    size_t o = (size_t)n * 262144 + (size_t)(o0 + dr) * HID + i0 + ic;
    #pragma unroll
    for (int c = 0; c < 4; ++c) {
        ushort4 v = make_ushort4(f2bf(tile[ic + c * 4 + 0][dr]), f2bf(tile[ic + c * 4 + 1][dr]),
                                 f2bf(tile[ic + c * 4 + 2][dr]), f2bf(tile[ic + c * 4 + 3][dr]));
        *(ushort4*)(WVt + o + c * 4) = v;
    }
}

// -----------------------------------------------------------------------------
// K4: fused MFMA attention with cross-iteration prefetch (double-buffered
// B-operand frags, unroll-2 so buffer indices constant-fold).
// USE_HT: phase C streams hT[b][d][e] from global (no LDS transpose).
// LDS 53504 B -> 3 blocks/CU.
// -----------------------------------------------------------------------------
template<bool USE_HT>
__global__ __launch_bounds__(256, 3) void attn_kernel(const u16* __restrict__ h_h,
                                                      const u16* __restrict__ h_l,
                                                      const u16* __restrict__ Mt_h,
                                                      const u16* __restrict__ Mt_l,
                                                      const u16* __restrict__ WVt,
                                                      const u16* __restrict__ hT,
                                                      float* __restrict__ out) {
    __shared__ __align__(16) char SM[53504];
    u16*   Th  = (u16*)SM;                    // [32][260]
    u16*   Tl  = (u16*)(SM + 16640);          // [32][260]
    float* S   = (float*)SM;                  // [256][33]
    float* red = (float*)(SM + 33792);        // [256]
    u16*   HbT = (u16*)SM;                    // [512][36] (fallback only)
    u16*   U   = (u16*)SM;                    // [32][520]
    u16*   Pt  = (u16*)(SM + 36864);          // [32][260]

    const int bid = blockIdx.x;
    const int x7 = bid & 7;
    const int s  = bid >> 3;
    const int at = s & 1;
    const int n  = (x7 >> 1) | (((s >> 1) & 1) << 2);
    const int b  = ((s >> 2) << 1) | (x7 & 1);

    const int tid  = threadIdx.x;
    const int wid  = tid >> 6;
    const int lane = tid & 63;
    const int l15  = lane & 15;
    const int quad = lane >> 4;

    const u16* Mth = Mt_h + (size_t)n * 262144;
    const u16* Mtl = Mt_l + (size_t)n * 262144;
    const u16* Wv  = WVt  + (size_t)n * 262144;
    const u16* hTb = hT + (size_t)b * 131072;
    const size_t hb_base = (size_t)b * NENT * HID;
    const size_t ha_base = hb_base + (size_t)at * 32 * HID;

    const floatx4 z4 = {0.f, 0.f, 0.f, 0.f};
    floatx4 Sacc[8];
    #pragma unroll
    for (int i = 0; i < 8; ++i) Sacc[i] = z4;

    for (int H = 0; H < 2; ++H) {
        // ---------- Phase A: T[:, H*256 + 0..255], Mt-frags double-buffered ----------
        floatx4 Tacc[8];
        #pragma unroll
        for (int i = 0; i < 8; ++i) Tacc[i] = z4;
        Frag Bh[2][4], Bl[2][4];
        auto loadBA = [&](int ksv, Frag* bh, Frag* bl) {
            const int k = ksv * 32 + quad * 8;
            #pragma unroll
            for (int nt = 0; nt < 4; ++nt) {
                const int d = H * 256 + (wid * 4 + nt) * 16 + l15;
                bh[nt].s = *(const u32x4*)(Mth + (size_t)d * HID + k);
                bl[nt].s = *(const u32x4*)(Mtl + (size_t)d * HID + k);
            }
        };
        loadBA(0, Bh[0], Bl[0]);
        #pragma unroll 2
        for (int ks = 0; ks < 16; ++ks) {
            const int cur = ks & 1, nxt = cur ^ 1;
            const int k = ks * 32 + quad * 8;
            Frag Ahf[2], Alf[2];
            #pragma unroll
            for (int mt = 0; mt < 2; ++mt) {
                const size_t ro = ha_base + (size_t)(mt * 16 + l15) * HID + k;
                Ahf[mt].s = *(const u32x4*)(h_h + ro);
                Alf[mt].s = *(const u32x4*)(h_l + ro);
            }
            if (ks < 15) loadBA(ks + 1, Bh[nxt], Bl[nxt]);
            #pragma unroll
            for (int nt = 0; nt < 4; ++nt)
                #pragma unroll
                for (int mt = 0; mt < 2; ++mt) {
                    floatx4 c = Tacc[mt * 4 + nt];
                    c = __builtin_amdgcn_mfma_f32_16x16x32_bf16(Ahf[mt].v, Bh[cur][nt].v, c, 0, 0, 0);
                    c = __builtin_amdgcn_mfma_f32_16x16x32_bf16(Ahf[mt].v, Bl[cur][nt].v, c, 0, 0, 0);
                    c = __builtin_amdgcn_mfma_f32_16x16x32_bf16(Alf[mt].v, Bh[cur][nt].v, c, 0, 0, 0);
                    Tacc[mt * 4 + nt] = c;
                }
        }
        __syncthreads();
        #pragma unroll
        for (int mt = 0; mt < 2; ++mt)
            #pragma unroll
            for (int nt = 0; nt < 4; ++nt)
                #pragma unroll
                for (int r = 0; r < 4; ++r) {
                    const float v = Tacc[mt * 4 + nt][r];
                    const int a  = mt * 16 + quad * 4 + r;
                    const int dl = (wid * 4 + nt) * 16 + l15;
                    const u16 hi = f2bf(v);
                    Th[a * 260 + dl] = hi;
                    Tl[a * 260 + dl] = f2bf(v - bf2f(hi));
                }
        __syncthreads();
        // ---------- Phase B: S^T += hb[:, half] @ T^T, hb-frags double-buffered ----------
        Frag Ahb[2][4], Alb[2][4];
        auto loadAB2 = [&](int ksv, Frag* ah, Frag* al) {
            const int kg = H * 256 + ksv * 32 + quad * 8;
            #pragma unroll
            for (int mt = 0; mt < 4; ++mt) {
                const size_t ro = hb_base + (size_t)((wid * 4 + mt) * 16 + l15) * HID + kg;
                ah[mt].s = *(const u32x4*)(h_h + ro);
                al[mt].s = *(const u32x4*)(h_l + ro);
            }
        };
        loadAB2(0, Ahb[0], Alb[0]);
        #pragma unroll 2
        for (int ks = 0; ks < 8; ++ks) {
            const int cur = ks & 1, nxt = cur ^ 1;
            const int kl = ks * 32 + quad * 8;
            if (ks < 7) loadAB2(ks + 1, Ahb[nxt], Alb[nxt]);
            #pragma unroll
            for (int nt = 0; nt < 2; ++nt) {
                const int ac = nt * 16 + l15;
                Frag Bfh, Bfl;
                Bfh.p.lo = *(const u32x2*)(Th + ac * 260 + kl);
                Bfh.p.hi = *(const u32x2*)(Th + ac * 260 + kl + 4);
                Bfl.p.lo = *(const u32x2*)(Tl + ac * 260 + kl);
                Bfl.p.hi = *(const u32x2*)(Tl + ac * 260 + kl + 4);
                #pragma unroll
                for (int mt = 0; mt < 4; ++mt) {
                    floatx4 c = Sacc[mt * 2 + nt];
                    c = __builtin_amdgcn_mfma_f32_16x16x32_bf16(Ahb[cur][mt].v, Bfh.v, c, 0, 0, 0);
                    c = __builtin_amdgcn_mfma_f32_16x16x32_bf16(Ahb[cur][mt].v, Bfl.v, c, 0, 0, 0);
                    c = __builtin_amdgcn_mfma_f32_16x16x32_bf16(Alb[cur][mt].v, Bfh.v, c, 0, 0, 0);
                    Sacc[mt * 2 + nt] = c;
                }
            }
        }
    }
    __syncthreads();
    #pragma unroll
    for (int mt = 0; mt < 4; ++mt)
        #pragma unroll
        for (int nt = 0; nt < 2; ++nt)
            #pragma unroll
            for (int r = 0; r < 4; ++r) {
                const int e = (wid * 4 + mt) * 16 + quad * 4 + r;
                const int a = nt * 16 + l15;
                S[e * 33 + a] = Sacc[mt * 2 + nt][r];
            }
    __syncthreads();
    // ---------- Softmax over e per agent ----------
    {
        const int a   = tid & 31;
        const int seg = tid >> 5;
        float v[32];
        #pragma unroll
        for (int i = 0; i < 32; ++i) v[i] = S[(seg * 32 + i) * 33 + a];
        float mx = v[0];
        #pragma unroll
        for (int i = 1; i < 32; ++i) mx = fmaxf(mx, v[i]);
        red[a * 8 + seg] = mx;
        __syncthreads();
        float gmx = red[a * 8 + 0];
        #pragma unroll
        for (int i = 1; i < 8; ++i) gmx = fmaxf(gmx, red[a * 8 + i]);
        __syncthreads();
        float sum = 0.f;
        #pragma unroll
        for (int i = 0; i < 32; ++i) { v[i] = expf(v[i] - gmx); sum += v[i]; }
        red[a * 8 + seg] = sum;
        __syncthreads();
        float tot = 0.f;
        #pragma unroll
        for (int i = 0; i < 8; ++i) tot += red[a * 8 + i];
        const float inv = 1.0f / tot;
        #pragma unroll
        for (int i = 0; i < 32; ++i)
            Pt[a * 260 + seg * 32 + i] = f2bf(v[i] * inv);
    }
    __syncthreads();
    // ---------- Phase C: U = P @ hb ----------
    floatx4 Uacc[16];
    #pragma unroll
    for (int i = 0; i < 16; ++i) Uacc[i] = z4;
    const int d0w = wid * 128;
    if (USE_HT) {
        // B-frags streamed from global hT[b][d][e], double-buffered
        Frag Bc[2][8];
        auto loadBC = [&](int etv, Frag* bc) {
            #pragma unroll
            for (int dt = 0; dt < 8; ++dt) {
                const int d = d0w + dt * 16 + l15;
                bc[dt].s = *(const u32x4*)(hTb + (size_t)d * 256 + etv * 32 + quad * 8);
            }
        };
        loadBC(0, Bc[0]);
        #pragma unroll 2
        for (int et = 0; et < 8; ++et) {
            const int cur = et & 1, nxt = cur ^ 1;
            if (et < 7) loadBC(et + 1, Bc[nxt]);
            Frag Ap[2];
            #pragma unroll
            for (int mt = 0; mt < 2; ++mt) {
                const int ar = mt * 16 + l15;
                Ap[mt].p.lo = *(const u32x2*)(Pt + ar * 260 + et * 32 + quad * 8);
                Ap[mt].p.hi = *(const u32x2*)(Pt + ar * 260 + et * 32 + quad * 8 + 4);
            }
            #pragma unroll
            for (int dt = 0; dt < 8; ++dt)
                #pragma unroll
                for (int mt = 0; mt < 2; ++mt)
                    Uacc[mt * 8 + dt] = __builtin_amdgcn_mfma_f32_16x16x32_bf16(Ap[mt].v, Bc[cur][dt].v, Uacc[mt * 8 + dt], 0, 0, 0);
        }
    } else {
        // fallback: pair-packed in-LDS transpose (proven path)
        u32* Hb32 = (u32*)HbT;
        for (int et = 0; et < 8; ++et) {
            {
                const int ep = lane & 15;
                const int q  = lane >> 4;
                const size_t r0 = hb_base + (size_t)(et * 32 + 2 * ep) * HID;
                #pragma unroll
                for (int c = 0; c < 4; ++c) {
                    const int d0 = d0w + c * 32 + q * 8;
                    u32x4 u0 = *(const u32x4*)(h_h + r0 + d0);
                    u32x4 u1 = *(const u32x4*)(h_h + r0 + HID + d0);
                    #pragma unroll
                    for (int p = 0; p < 4; ++p) {
                        const u32 w0 = (u0[p] & 0xFFFFu) | (u1[p] << 16);
                        const u32 w1 = (u0[p] >> 16) | (u1[p] & 0xFFFF0000u);
                        Hb32[(d0 + 2 * p) * 18 + ep]     = w0;
                        Hb32[(d0 + 2 * p + 1) * 18 + ep] = w1;
                    }
                }
            }
            Frag Ap[2];
            #pragma unroll
            for (int mt = 0; mt < 2; ++mt) {
                const int ar = mt * 16 + l15;
                Ap[mt].p.lo = *(const u32x2*)(Pt + ar * 260 + et * 32 + quad * 8);
                Ap[mt].p.hi = *(const u32x2*)(Pt + ar * 260 + et * 32 + quad * 8 + 4);
            }
            #pragma unroll
            for (int dt = 0; dt < 8; ++dt) {
                const int d = d0w + dt * 16 + l15;
                Frag Bf;
                Bf.p.lo = *(const u32x2*)(HbT + d * 36 + quad * 8);
                Bf.p.hi = *(const u32x2*)(HbT + d * 36 + quad * 8 + 4);
                #pragma unroll
                for (int mt = 0; mt < 2; ++mt)
                    Uacc[mt * 8 + dt] = __builtin_amdgcn_mfma_f32_16x16x32_bf16(Ap[mt].v, Bf.v, Uacc[mt * 8 + dt], 0, 0, 0);
            }
        }
    }
    __syncthreads();
    #pragma unroll
    for (int mt = 0; mt < 2; ++mt)
        #pragma unroll
        for (int dt = 0; dt < 8; ++dt)
            #pragma unroll
            for (int r = 0; r < 4; ++r) {
                const int a = mt * 16 + quad * 4 + r;
                const int d = d0w + dt * 16 + l15;
                U[a * 520 + d] = f2bf(Uacc[mt * 8 + dt][r]);
            }
    __syncthreads();
    // ---------- Phase D: z = U @ WVt, Wv-frags double-buffered ----------
    floatx4 Zacc[16];
    #pragma unroll
    for (int i = 0; i < 16; ++i) Zacc[i] = z4;
    Frag Bw[2][8];
    auto loadBD = [&](int ksv, Frag* bw) {
        const int k = ksv * 32 + quad * 8;
        #pragma unroll
        for (int dt = 0; dt < 8; ++dt) {
            const int dn = (wid * 8 + dt) * 16 + l15;
            bw[dt].s = *(const u32x4*)(Wv + (size_t)dn * HID + k);
        }
    };
    loadBD(0, Bw[0]);
    #pragma unroll 2
    for (int ks = 0; ks < 16; ++ks) {
        const int cur = ks & 1, nxt = cur ^ 1;
        const int k = ks * 32 + quad * 8;
        Frag Au[2];
        #pragma unroll
        for (int mt = 0; mt < 2; ++mt) {
            Au[mt].p.lo = *(const u32x2*)(U + (mt * 16 + l15) * 520 + k);
            Au[mt].p.hi = *(const u32x2*)(U + (mt * 16 + l15) * 520 + k + 4);
        }
        if (ks < 15) loadBD(ks + 1, Bw[nxt]);
        #pragma unroll
        for (int dt = 0; dt < 8; ++dt)
            #pragma unroll
            for (int mt = 0; mt < 2; ++mt)
                Zacc[mt * 8 + dt] = __builtin_amdgcn_mfma_f32_16x16x32_bf16(Au[mt].v, Bw[cur][dt].v, Zacc[mt * 8 + dt], 0, 0, 0);
    }
    float* ob = out + ((size_t)b * NAGENT + at * 32) * HID;
    #pragma unroll
    for (int mt = 0; mt < 2; ++mt)
        #pragma unroll
        for (int dt = 0; dt < 8; ++dt)
            #pragma unroll
            for (int r = 0; r < 4; ++r) {
                const int a  = mt * 16 + quad * 4 + r;
                const int dn = (wid * 8 + dt) * 16 + l15;
                atomicAdd(ob + (size_t)a * HID + dn, Zacc[mt * 8 + dt][r] * 0.125f);
            }
}

// -----------------------------------------------------------------------------
// ws layout: h_h 32M | h_l 32M | Mt_h 4M | Mt_l 4M | WVt 4M  (76 MB proven)
//            | hT 32M (only if ws_size >= 108 MB; else fallback path)
// -----------------------------------------------------------------------------
extern "C" void kernel_launch(void* const* d_in, const int* in_sizes, int n_in,
                              void* d_out, int out_size, void* d_ws, size_t ws_size,
                              hipStream_t stream) {
    const float* x     = (const float*)d_in[0];
    const float* W_enc = (const float*)d_in[1];
    const float* b_enc = (const float*)d_in[2];
    const float* WQ    = (const float*)d_in[3];
    const float* WK    = (const float*)d_in[4];
    const float* WV    = (const float*)d_in[5];
    float* out = (float*)d_out;

    char* ws = (char*)d_ws;
    u16* h_h  = (u16*)ws;
    u16* h_l  = (u16*)(ws + 33554432);
    u16* Mt_h = (u16*)(ws + 67108864);
    u16* Mt_l = (u16*)(ws + 71303168);
    u16* WVt  = (u16*)(ws + 75497472);
    u16* hT   = (u16*)(ws + 79691776);
    u16* Wt_h = WVt;                       // transient, 256 KB
    u16* Wt_l = WVt + 131072;              // transient, 256 KB

    const bool useHT = ws_size >= (size_t)113246208;  // 108 MB

    hipMemsetAsync(d_out, 0, (size_t)out_size * sizeof(float), stream);
    wenc_t_kernel<<<32, 256, 0, stream>>>(W_enc, Wt_h, Wt_l);
    enc_kernel<<<1024, 256, 0, stream>>>(x, Wt_h, Wt_l, b_enc, h_h, h_l);
    if (useHT) ht_kernel<<<4096, 256, 0, stream>>>(h_h, hT);
    wvt_kernel<<<512, 256, 0, stream>>>(WV, WVt);
    wqk_kernel<<<512, 256, 0, stream>>>(WQ, WK, Mt_h, Mt_l);
    if (useHT)
        attn_kernel<true><<<2048, 256, 0, stream>>>(h_h, h_l, Mt_h, Mt_l, WVt, hT, out);
    else
        attn_kernel<false><<<2048, 256, 0, stream>>>(h_h, h_l, Mt_h, Mt_l, WVt, hT, out);
}

// Round 5
// 967.139 us; speedup vs baseline: 1.0228x; 1.0228x over previous
//
#include <hip/hip_runtime.h>
#include <math.h>

#define BATCH  128
#define NENT   256
#define INDIM  256
#define HID    512
#define NHEAD  8
#define NAGENT 64
#define SCALE  0.04419417382415922f   // 1/sqrt(512)

// Packed split-bf16 layout: row-major rows of k-blocks; each 32-k block is
// 128 B = [32 x u16 hi | 32 x u16 lo] -> one full cache line per frag pair.
// h_p:  [32768][16 blk][64]  (64 MB)   Mt_p: [8][512][16 blk][64] (8 MB)
// Wt_p: [512][8 blk][64] (512 KB, transient)

typedef unsigned short u16;
typedef unsigned int   u32;

typedef __bf16 bf16x8  __attribute__((ext_vector_type(8)));
typedef float  floatx4 __attribute__((ext_vector_type(4)));
typedef u32    u32x4   __attribute__((ext_vector_type(4)));
typedef u32    u32x2   __attribute__((ext_vector_type(2)));

union Frag {
    u32x4 s;
    struct { u32x2 lo, hi; } p;
    bf16x8 v;
};

__device__ __forceinline__ u16 f2bf(float x) {
    u32 u = __float_as_uint(x);
    return (u16)((u + 0x7FFFu + ((u >> 16) & 1u)) >> 16);
}
__device__ __forceinline__ float bf2f(u16 b) {
    return __uint_as_float(((u32)b) << 16);
}
__device__ __forceinline__ void split4(const float4& r, ushort4& hh, ushort4& hl) {
    hh.x = f2bf(r.x); hl.x = f2bf(r.x - bf2f(hh.x));
    hh.y = f2bf(r.y); hl.y = f2bf(r.y - bf2f(hh.y));
    hh.z = f2bf(r.z); hl.z = f2bf(r.z - bf2f(hh.z));
    hh.w = f2bf(r.w); hl.w = f2bf(r.w - bf2f(hh.w));
}

// -----------------------------------------------------------------------------
// K0: Wt_p[d][k] = packed split(W_enc[k][d])  (transpose), 512 x 256
// -----------------------------------------------------------------------------
__global__ __launch_bounds__(256) void wenc_t_kernel(const float* __restrict__ W,
                                                     u16* __restrict__ Wt_p) {
    __shared__ float tile[64][68];
    const int bid = blockIdx.x;          // 4 k-tiles x 8 d-tiles
    const int k0 = (bid & 3) * 64;
    const int d0 = (bid >> 2) * 64;
    const int t = threadIdx.x;
    const int ki = t >> 2, dc = (t & 3) * 16;
    #pragma unroll
    for (int c = 0; c < 4; ++c)
        *(float4*)&tile[ki][dc + c * 4] =
            *(const float4*)(W + (size_t)(k0 + ki) * HID + d0 + dc + c * 4);
    __syncthreads();
    const int dr = t >> 2, kc = (t & 3) * 16;
    #pragma unroll
    for (int c = 0; c < 4; ++c) {
        float4 v = make_float4(tile[kc + c * 4 + 0][dr], tile[kc + c * 4 + 1][dr],
                               tile[kc + c * 4 + 2][dr], tile[kc + c * 4 + 3][dr]);
        ushort4 hh, hl; split4(v, hh, hl);
        const int kk = k0 + kc + c * 4;
        size_t o = (size_t)(d0 + dr) * 512 + (size_t)(kk >> 5) * 64 + (kk & 31);
        *(ushort4*)(Wt_p + o) = hh;
        *(ushort4*)(Wt_p + o + 32) = hl;
    }
}

// -----------------------------------------------------------------------------
// K1: h = leaky_relu(x) @ W_enc + b_enc via split-bf16 3-pass MFMA -> h_p packed
// -----------------------------------------------------------------------------
__global__ __launch_bounds__(256) void enc_kernel(const float* __restrict__ x,
                                                  const u16* __restrict__ Wt_p,
                                                  const float* __restrict__ bias,
                                                  u16* __restrict__ h_p) {
    __shared__ u16 Ah[32][264];
    __shared__ u16 Al[32][264];
    const int r0 = blockIdx.x * 32;
    const int t  = threadIdx.x;
    {
        const int row = t >> 3;
        const float* xr = x + (size_t)(r0 + row) * INDIM;
        #pragma unroll
        for (int j = 0; j < 8; ++j) {
            const int k0 = ((t & 7) + j * 8) * 4;
            float4 v = *(const float4*)(xr + k0);
            v.x = v.x > 0.f ? v.x : 0.01f * v.x;
            v.y = v.y > 0.f ? v.y : 0.01f * v.y;
            v.z = v.z > 0.f ? v.z : 0.01f * v.z;
            v.w = v.w > 0.f ? v.w : 0.01f * v.w;
            ushort4 hh, hl; split4(v, hh, hl);
            *(ushort4*)&Ah[row][k0] = hh;
            *(ushort4*)&Al[row][k0] = hl;
        }
    }
    __syncthreads();

    const int wid = t >> 6, lane = t & 63, l15 = lane & 15, quad = lane >> 4;
    const int mbase = (wid & 1) * 16;
    const int nbase = (wid >> 1) * 256;
    const floatx4 z4 = {0.f, 0.f, 0.f, 0.f};
    floatx4 acc[16];
    #pragma unroll
    for (int i = 0; i < 16; ++i) acc[i] = z4;

    for (int ks = 0; ks < 8; ++ks) {
        const int k = ks * 32 + quad * 8;
        Frag Afh, Afl;
        Afh.s = *(const u32x4*)&Ah[mbase + l15][k];
        Afl.s = *(const u32x4*)&Al[mbase + l15][k];
        #pragma unroll
        for (int nt = 0; nt < 16; ++nt) {
            const int d = nbase + nt * 16 + l15;
            const size_t wo = (size_t)d * 512 + (size_t)ks * 64 + quad * 8;
            Frag Bh, Bl;
            Bh.s = *(const u32x4*)(Wt_p + wo);
            Bl.s = *(const u32x4*)(Wt_p + wo + 32);
            floatx4 c = acc[nt];
            c = __builtin_amdgcn_mfma_f32_16x16x32_bf16(Afh.v, Bh.v, c, 0, 0, 0);
            c = __builtin_amdgcn_mfma_f32_16x16x32_bf16(Afh.v, Bl.v, c, 0, 0, 0);
            c = __builtin_amdgcn_mfma_f32_16x16x32_bf16(Afl.v, Bh.v, c, 0, 0, 0);
            acc[nt] = c;
        }
    }
    #pragma unroll
    for (int nt = 0; nt < 16; ++nt) {
        const int d = nbase + nt * 16 + l15;
        const float bv = bias[d];
        #pragma unroll
        for (int r = 0; r < 4; ++r) {
            const float v = acc[nt][r] + bv;
            const u16 hi = f2bf(v);
            const u16 lo = f2bf(v - bf2f(hi));
            const size_t o = (size_t)(r0 + mbase + quad * 4 + r) * 1024
                           + (size_t)(d >> 5) * 64 + (d & 31);
            h_p[o]      = hi;
            h_p[o + 32] = lo;
        }
    }
}

// -----------------------------------------------------------------------------
// K1b: hT[b][d][e] = hi(h[b*256+e][d])  (64x64 u16 tile transpose, from packed)
// -----------------------------------------------------------------------------
__global__ __launch_bounds__(256) void ht_kernel(const u16* __restrict__ h_p,
                                                 u16* __restrict__ hT) {
    __shared__ u16 tile[64][72];
    const int bid = blockIdx.x;               // 8 dt x 4 et x 128 b
    const int dt = bid & 7;
    const int et = (bid >> 3) & 3;
    const int b  = bid >> 5;
    const int t  = threadIdx.x;
    const int r  = t >> 2, cs = (t & 3) * 16;
    const int dg = dt * 64 + cs;
    const u16* src = h_p + (size_t)(b * 256 + et * 64 + r) * 1024
                   + (size_t)(dg >> 5) * 64 + (dg & 31);
    *(ushort4*)&tile[r][cs + 0]  = *(const ushort4*)(src + 0);
    *(ushort4*)&tile[r][cs + 4]  = *(const ushort4*)(src + 4);
    *(ushort4*)&tile[r][cs + 8]  = *(const ushort4*)(src + 8);
    *(ushort4*)&tile[r][cs + 12] = *(const ushort4*)(src + 12);
    __syncthreads();
    const int d = t >> 2, es = (t & 3) * 16;
    u16* dst = hT + (size_t)b * 131072 + (size_t)(dt * 64 + d) * 256 + et * 64 + es;
    #pragma unroll
    for (int c = 0; c < 4; ++c) {
        ushort4 v = make_ushort4(tile[es + c * 4 + 0][d], tile[es + c * 4 + 1][d],
                                 tile[es + c * 4 + 2][d], tile[es + c * 4 + 3][d]);
        *(ushort4*)(dst + c * 4) = v;
    }
}

// -----------------------------------------------------------------------------
// K2: Mt_p[n][j][i] = packed split(SCALE * dot(WQ[n][i,:], WK[n][j,:]))
// -----------------------------------------------------------------------------
__global__ __launch_bounds__(256) void wqk_kernel(const float* __restrict__ WQ,
                                                  const float* __restrict__ WK,
                                                  u16* __restrict__ Mt_p) {
    __shared__ u16 Ah[64][72], Al[64][72], Bh[64][72], Bl[64][72];
    const int bid = blockIdx.x;
    const int jt = (bid & 7) * 64;
    const int it = ((bid >> 3) & 7) * 64;
    const int n  = bid >> 6;
    const float* qp = WQ + (size_t)n * 262144;
    const float* kp = WK + (size_t)n * 262144;
    const int t = threadIdx.x;
    const int wid = t >> 6, lane = t & 63, l15 = lane & 15, quad = lane >> 4;
    const int srow = t >> 2, sc = (t & 3) * 16;

    const floatx4 z4 = {0.f, 0.f, 0.f, 0.f};
    floatx4 acc[4];
    #pragma unroll
    for (int i = 0; i < 4; ++i) acc[i] = z4;

    for (int kc = 0; kc < HID; kc += 64) {
        #pragma unroll
        for (int f = 0; f < 4; ++f) {
            float4 va = *(const float4*)(kp + (size_t)(jt + srow) * HID + kc + sc + f * 4);
            ushort4 hh, hl; split4(va, hh, hl);
            *(ushort4*)&Ah[srow][sc + f * 4] = hh;
            *(ushort4*)&Al[srow][sc + f * 4] = hl;
            float4 vb = *(const float4*)(qp + (size_t)(it + srow) * HID + kc + sc + f * 4);
            split4(vb, hh, hl);
            *(ushort4*)&Bh[srow][sc + f * 4] = hh;
            *(ushort4*)&Bl[srow][sc + f * 4] = hl;
        }
        __syncthreads();
        #pragma unroll
        for (int ks = 0; ks < 2; ++ks) {
            const int k = ks * 32 + quad * 8;
            Frag Afh, Afl;
            Afh.s = *(const u32x4*)&Ah[wid * 16 + l15][k];
            Afl.s = *(const u32x4*)&Al[wid * 16 + l15][k];
            #pragma unroll
            for (int nt = 0; nt < 4; ++nt) {
                Frag Bfh, Bfl;
                Bfh.s = *(const u32x4*)&Bh[nt * 16 + l15][k];
                Bfl.s = *(const u32x4*)&Bl[nt * 16 + l15][k];
                floatx4 c = acc[nt];
                c = __builtin_amdgcn_mfma_f32_16x16x32_bf16(Afh.v, Bfh.v, c, 0, 0, 0);
                c = __builtin_amdgcn_mfma_f32_16x16x32_bf16(Afh.v, Bfl.v, c, 0, 0, 0);
                c = __builtin_amdgcn_mfma_f32_16x16x32_bf16(Afl.v, Bfh.v, c, 0, 0, 0);
                acc[nt] = c;
            }
        }
        __syncthreads();
    }
    #pragma unroll
    for (int nt = 0; nt < 4; ++nt)
        #pragma unroll
        for (int r = 0; r < 4; ++r) {
            const float v = acc[nt][r] * SCALE;
            const u16 hi = f2bf(v);
            const u16 lo = f2bf(v - bf2f(hi));
            const int j = jt + wid * 16 + quad * 4 + r;
            const int i = it + nt * 16 + l15;
            const size_t o = (size_t)n * 524288 + (size_t)j * 1024
                           + (size_t)(i >> 5) * 64 + (i & 31);
            Mt_p[o]      = hi;
            Mt_p[o + 32] = lo;
        }
}

// -----------------------------------------------------------------------------
// K3: WVt[n][dout][din] = bf16(WV[n][din][dout])
// -----------------------------------------------------------------------------
__global__ __launch_bounds__(256) void wvt_kernel(const float* __restrict__ WV,
                                                  u16* __restrict__ WVt) {
    __shared__ float tile[64][68];
    const int bid = blockIdx.x;
    const int i0 = (bid & 7) * 64;
    const int o0 = ((bid >> 3) & 7) * 64;
    const int n  = bid >> 6;
    const float* src = WV + (size_t)n * 262144;
    const int t  = threadIdx.x;
    const int di = t >> 2;
    const int dc = (t & 3) * 16;
    #pragma unroll
    for (int c = 0; c < 4; ++c)
        *(float4*)&tile[di][dc + c * 4] =
            *(const float4*)(src + (size_t)(i0 + di) * HID + o0 + dc + c * 4);
    __syncthreads();
    const int dr = t >> 2;
    const int ic = (t & 3) * 16;
    size_t o = (size_t)n * 262144 + (size_t)(o0 + dr) * HID + i0 + ic;
    #pragma unroll
    for (int c = 0; c < 4; ++c) {
        ushort4 v = make_ushort4(f2bf(tile[ic + c * 4 + 0][dr]), f2bf(tile[ic + c * 4 + 1][dr]),
                                 f2bf(tile[ic + c * 4 + 2][dr]), f2bf(tile[ic + c * 4 + 3][dr]));
        *(ushort4*)(WVt + o + c * 4) = v;
    }
}

// -----------------------------------------------------------------------------
// K4: fused MFMA attention, line-dense packed loads.
//   A: T = ha@Mt (split 3-pass, packed hi|lo lines)
//   B: S^T = hb@T^T (split, packed A-frags)
//   softmax -> Pt
//   C: U = P@hb via hT, et-paired loads (full-line consumption)
//   D: z = U@WVt, ks-paired loads (full-line consumption)
// LDS 53504 B -> 3 blocks/CU.
// -----------------------------------------------------------------------------
template<bool USE_HT>
__global__ __launch_bounds__(256, 3) void attn_kernel(const u16* __restrict__ h_p,
                                                      const u16* __restrict__ Mt_p,
                                                      const u16* __restrict__ WVt,
                                                      const u16* __restrict__ hT,
                                                      float* __restrict__ out) {
    __shared__ __align__(16) char SM[53504];
    u16*   Th  = (u16*)SM;                    // [32][260]
    u16*   Tl  = (u16*)(SM + 16640);          // [32][260]
    float* S   = (float*)SM;                  // [256][33]
    float* red = (float*)(SM + 33792);        // [256]
    u16*   HbT = (u16*)SM;                    // [512][36] (fallback only)
    u16*   U   = (u16*)SM;                    // [32][520]
    u16*   Pt  = (u16*)(SM + 36864);          // [32][260]

    const int bid = blockIdx.x;
    const int x7 = bid & 7;
    const int s  = bid >> 3;
    const int at = s & 1;
    const int n  = (x7 >> 1) | (((s >> 1) & 1) << 2);
    const int b  = ((s >> 2) << 1) | (x7 & 1);

    const int tid  = threadIdx.x;
    const int wid  = tid >> 6;
    const int lane = tid & 63;
    const int l15  = lane & 15;
    const int quad = lane >> 4;

    const u16* Mtp = Mt_p + (size_t)n * 524288;
    const u16* Wv  = WVt  + (size_t)n * 262144;
    const u16* hTb = hT + (size_t)b * 131072;
    const size_t hb_base = (size_t)b * 262144;            // packed rows of 1024
    const size_t ha_row0 = hb_base + (size_t)(at * 32) * 1024;

    const floatx4 z4 = {0.f, 0.f, 0.f, 0.f};
    floatx4 Sacc[8];
    #pragma unroll
    for (int i = 0; i < 8; ++i) Sacc[i] = z4;

    for (int H = 0; H < 2; ++H) {
        // ---------- Phase A: T[:, H*256 + 0..255] ----------
        floatx4 Tacc[8];
        #pragma unroll
        for (int i = 0; i < 8; ++i) Tacc[i] = z4;
        for (int ks = 0; ks < 16; ++ks) {
            const int ko = ks * 64 + quad * 8;            // packed block offset
            Frag Ahf[2], Alf[2];
            #pragma unroll
            for (int mt = 0; mt < 2; ++mt) {
                const size_t ro = ha_row0 + (size_t)(mt * 16 + l15) * 1024 + ko;
                Ahf[mt].s = *(const u32x4*)(h_p + ro);
                Alf[mt].s = *(const u32x4*)(h_p + ro + 32);
            }
            #pragma unroll
            for (int nt = 0; nt < 4; ++nt) {
                const int d = H * 256 + (wid * 4 + nt) * 16 + l15;
                const size_t mo = (size_t)d * 1024 + ko;
                Frag Bh, Bl;
                Bh.s = *(const u32x4*)(Mtp + mo);
                Bl.s = *(const u32x4*)(Mtp + mo + 32);
                #pragma unroll
                for (int mt = 0; mt < 2; ++mt) {
                    floatx4 c = Tacc[mt * 4 + nt];
                    c = __builtin_amdgcn_mfma_f32_16x16x32_bf16(Ahf[mt].v, Bh.v, c, 0, 0, 0);
                    c = __builtin_amdgcn_mfma_f32_16x16x32_bf16(Ahf[mt].v, Bl.v, c, 0, 0, 0);
                    c = __builtin_amdgcn_mfma_f32_16x16x32_bf16(Alf[mt].v, Bh.v, c, 0, 0, 0);
                    Tacc[mt * 4 + nt] = c;
                }
            }
        }
        __syncthreads();
        #pragma unroll
        for (int mt = 0; mt < 2; ++mt)
            #pragma unroll
            for (int nt = 0; nt < 4; ++nt)
                #pragma unroll
                for (int r = 0; r < 4; ++r) {
                    const float v = Tacc[mt * 4 + nt][r];
                    const int a  = mt * 16 + quad * 4 + r;
                    const int dl = (wid * 4 + nt) * 16 + l15;
                    const u16 hi = f2bf(v);
                    Th[a * 260 + dl] = hi;
                    Tl[a * 260 + dl] = f2bf(v - bf2f(hi));
                }
        __syncthreads();
        // ---------- Phase B: S^T += hb[:, H-half] @ T^T ----------
        for (int ks = 0; ks < 8; ++ks) {
            const int kl = ks * 32 + quad * 8;            // local (LDS) k
            const int ko = (H * 8 + ks) * 64 + quad * 8;  // packed global k
            Frag Ahf[4], Alf[4];
            #pragma unroll
            for (int mt = 0; mt < 4; ++mt) {
                const size_t ro = hb_base + (size_t)((wid * 4 + mt) * 16 + l15) * 1024 + ko;
                Ahf[mt].s = *(const u32x4*)(h_p + ro);
                Alf[mt].s = *(const u32x4*)(h_p + ro + 32);
            }
            #pragma unroll
            for (int nt = 0; nt < 2; ++nt) {
                const int ac = nt * 16 + l15;
                Frag Bfh, Bfl;
                Bfh.p.lo = *(const u32x2*)(Th + ac * 260 + kl);
                Bfh.p.hi = *(const u32x2*)(Th + ac * 260 + kl + 4);
                Bfl.p.lo = *(const u32x2*)(Tl + ac * 260 + kl);
                Bfl.p.hi = *(const u32x2*)(Tl + ac * 260 + kl + 4);
                #pragma unroll
                for (int mt = 0; mt < 4; ++mt) {
                    floatx4 c = Sacc[mt * 2 + nt];
                    c = __builtin_amdgcn_mfma_f32_16x16x32_bf16(Ahf[mt].v, Bfh.v, c, 0, 0, 0);
                    c = __builtin_amdgcn_mfma_f32_16x16x32_bf16(Ahf[mt].v, Bfl.v, c, 0, 0, 0);
                    c = __builtin_amdgcn_mfma_f32_16x16x32_bf16(Alf[mt].v, Bfh.v, c, 0, 0, 0);
                    Sacc[mt * 2 + nt] = c;
                }
            }
        }
    }
    __syncthreads();
    #pragma unroll
    for (int mt = 0; mt < 4; ++mt)
        #pragma unroll
        for (int nt = 0; nt < 2; ++nt)
            #pragma unroll
            for (int r = 0; r < 4; ++r) {
                const int e = (wid * 4 + mt) * 16 + quad * 4 + r;
                const int a = nt * 16 + l15;
                S[e * 33 + a] = Sacc[mt * 2 + nt][r];
            }
    __syncthreads();
    // ---------- Softmax over e per agent ----------
    {
        const int a   = tid & 31;
        const int seg = tid >> 5;
        float v[32];
        #pragma unroll
        for (int i = 0; i < 32; ++i) v[i] = S[(seg * 32 + i) * 33 + a];
        float mx = v[0];
        #pragma unroll
        for (int i = 1; i < 32; ++i) mx = fmaxf(mx, v[i]);
        red[a * 8 + seg] = mx;
        __syncthreads();
        float gmx = red[a * 8 + 0];
        #pragma unroll
        for (int i = 1; i < 8; ++i) gmx = fmaxf(gmx, red[a * 8 + i]);
        __syncthreads();
        float sum = 0.f;
        #pragma unroll
        for (int i = 0; i < 32; ++i) { v[i] = expf(v[i] - gmx); sum += v[i]; }
        red[a * 8 + seg] = sum;
        __syncthreads();
        float tot = 0.f;
        #pragma unroll
        for (int i = 0; i < 8; ++i) tot += red[a * 8 + i];
        const float inv = 1.0f / tot;
        #pragma unroll
        for (int i = 0; i < 32; ++i)
            Pt[a * 260 + seg * 32 + i] = f2bf(v[i] * inv);
    }
    __syncthreads();
    // ---------- Phase C: U = P @ hb ----------
    floatx4 Uacc[16];
    #pragma unroll
    for (int i = 0; i < 16; ++i) Uacc[i] = z4;
    const int d0w = wid * 128;
    if (USE_HT) {
        // et-paired: both 64B halves of each hT line consumed together
        for (int ep = 0; ep < 4; ++ep) {
            Frag Bc[2][8];
            #pragma unroll
            for (int sb = 0; sb < 2; ++sb)
                #pragma unroll
                for (int dt = 0; dt < 8; ++dt) {
                    const int d = d0w + dt * 16 + l15;
                    Bc[sb][dt].s = *(const u32x4*)(hTb + (size_t)d * 256
                                                   + (2 * ep + sb) * 32 + quad * 8);
                }
            #pragma unroll
            for (int sb = 0; sb < 2; ++sb) {
                const int et = 2 * ep + sb;
                Frag Ap[2];
                #pragma unroll
                for (int mt = 0; mt < 2; ++mt) {
                    const int ar = mt * 16 + l15;
                    Ap[mt].p.lo = *(const u32x2*)(Pt + ar * 260 + et * 32 + quad * 8);
                    Ap[mt].p.hi = *(const u32x2*)(Pt + ar * 260 + et * 32 + quad * 8 + 4);
                }
                #pragma unroll
                for (int dt = 0; dt < 8; ++dt)
                    #pragma unroll
                    for (int mt = 0; mt < 2; ++mt)
                        Uacc[mt * 8 + dt] = __builtin_amdgcn_mfma_f32_16x16x32_bf16(
                            Ap[mt].v, Bc[sb][dt].v, Uacc[mt * 8 + dt], 0, 0, 0);
            }
        }
    } else {
        // fallback: pair-packed in-LDS transpose from packed h (hi halves)
        u32* Hb32 = (u32*)HbT;
        for (int et = 0; et < 8; ++et) {
            {
                const int epi = lane & 15;
                const int q   = lane >> 4;
                const size_t r0p = hb_base + (size_t)(et * 32 + 2 * epi) * 1024;
                #pragma unroll
                for (int c = 0; c < 4; ++c) {
                    const int d0 = d0w + c * 32 + q * 8;
                    const size_t po = (size_t)(d0 >> 5) * 64 + (d0 & 31);
                    u32x4 u0 = *(const u32x4*)(h_p + r0p + po);
                    u32x4 u1 = *(const u32x4*)(h_p + r0p + 1024 + po);
                    #pragma unroll
                    for (int p = 0; p < 4; ++p) {
                        const u32 w0 = (u0[p] & 0xFFFFu) | (u1[p] << 16);
                        const u32 w1 = (u0[p] >> 16) | (u1[p] & 0xFFFF0000u);
                        Hb32[(d0 + 2 * p) * 18 + epi]     = w0;
                        Hb32[(d0 + 2 * p + 1) * 18 + epi] = w1;
                    }
                }
            }
            Frag Ap[2];
            #pragma unroll
            for (int mt = 0; mt < 2; ++mt) {
                const int ar = mt * 16 + l15;
                Ap[mt].p.lo = *(const u32x2*)(Pt + ar * 260 + et * 32 + quad * 8);
                Ap[mt].p.hi = *(const u32x2*)(Pt + ar * 260 + et * 32 + quad * 8 + 4);
            }
            #pragma unroll
            for (int dt = 0; dt < 8; ++dt) {
                const int d = d0w + dt * 16 + l15;
                Frag Bf;
                Bf.p.lo = *(const u32x2*)(HbT + d * 36 + quad * 8);
                Bf.p.hi = *(const u32x2*)(HbT + d * 36 + quad * 8 + 4);
                #pragma unroll
                for (int mt = 0; mt < 2; ++mt)
                    Uacc[mt * 8 + dt] = __builtin_amdgcn_mfma_f32_16x16x32_bf16(
                        Ap[mt].v, Bf.v, Uacc[mt * 8 + dt], 0, 0, 0);
            }
        }
    }
    __syncthreads();
    #pragma unroll
    for (int mt = 0; mt < 2; ++mt)
        #pragma unroll
        for (int dt = 0; dt < 8; ++dt)
            #pragma unroll
            for (int r = 0; r < 4; ++r) {
                const int a = mt * 16 + quad * 4 + r;
                const int d = d0w + dt * 16 + l15;
                U[a * 520 + d] = f2bf(Uacc[mt * 8 + dt][r]);
            }
    __syncthreads();
    // ---------- Phase D: z = U @ WVt, ks-paired (full-line consumption) ----------
    floatx4 Zacc[16];
    #pragma unroll
    for (int i = 0; i < 16; ++i) Zacc[i] = z4;
    for (int kp = 0; kp < 8; ++kp) {
        Frag Bw[2][8];
        #pragma unroll
        for (int sb = 0; sb < 2; ++sb) {
            const int k = (kp * 2 + sb) * 32 + quad * 8;
            #pragma unroll
            for (int dt = 0; dt < 8; ++dt) {
                const int dn = (wid * 8 + dt) * 16 + l15;
                Bw[sb][dt].s = *(const u32x4*)(Wv + (size_t)dn * HID + k);
            }
        }
        #pragma unroll
        for (int sb = 0; sb < 2; ++sb) {
            const int k = (kp * 2 + sb) * 32 + quad * 8;
            Frag Au[2];
            #pragma unroll
            for (int mt = 0; mt < 2; ++mt) {
                Au[mt].p.lo = *(const u32x2*)(U + (mt * 16 + l15) * 520 + k);
                Au[mt].p.hi = *(const u32x2*)(U + (mt * 16 + l15) * 520 + k + 4);
            }
            #pragma unroll
            for (int dt = 0; dt < 8; ++dt)
                #pragma unroll
                for (int mt = 0; mt < 2; ++mt)
                    Zacc[mt * 8 + dt] = __builtin_amdgcn_mfma_f32_16x16x32_bf16(
                        Au[mt].v, Bw[sb][dt].v, Zacc[mt * 8 + dt], 0, 0, 0);
        }
    }
    float* ob = out + ((size_t)b * NAGENT + at * 32) * HID;
    #pragma unroll
    for (int mt = 0; mt < 2; ++mt)
        #pragma unroll
        for (int dt = 0; dt < 8; ++dt)
            #pragma unroll
            for (int r = 0; r < 4; ++r) {
                const int a  = mt * 16 + quad * 4 + r;
                const int dn = (wid * 8 + dt) * 16 + l15;
                atomicAdd(ob + (size_t)a * HID + dn, Zacc[mt * 8 + dt][r] * 0.125f);
            }
}

// -----------------------------------------------------------------------------
// ws layout: h_p 64M [0,64M) | Mt_p 8M [64M,72M) | WVt 4M [72M,76M)
//            | hT 32M [76M,108M) (useHT iff ws >= 108 MB; proven in R4)
// Wt_p (512 KB) transiently lives at WVt start: wenc_t -> enc -> wvt overwrites.
// -----------------------------------------------------------------------------
extern "C" void kernel_launch(void* const* d_in, const int* in_sizes, int n_in,
                              void* d_out, int out_size, void* d_ws, size_t ws_size,
                              hipStream_t stream) {
    const float* x     = (const float*)d_in[0];
    const float* W_enc = (const float*)d_in[1];
    const float* b_enc = (const float*)d_in[2];
    const float* WQ    = (const float*)d_in[3];
    const float* WK    = (const float*)d_in[4];
    const float* WV    = (const float*)d_in[5];
    float* out = (float*)d_out;

    char* ws = (char*)d_ws;
    u16* h_p  = (u16*)ws;
    u16* Mt_p = (u16*)(ws + 67108864);
    u16* WVt  = (u16*)(ws + 75497472);
    u16* hT   = (u16*)(ws + 79691776);
    u16* Wt_p = WVt;                       // transient, 512 KB

    const bool useHT = ws_size >= (size_t)113246208;  // 108 MB

    hipMemsetAsync(d_out, 0, (size_t)out_size * sizeof(float), stream);
    wenc_t_kernel<<<32, 256, 0, stream>>>(W_enc, Wt_p);
    enc_kernel<<<1024, 256, 0, stream>>>(x, Wt_p, b_enc, h_p);
    if (useHT) ht_kernel<<<4096, 256, 0, stream>>>(h_p, hT);
    wvt_kernel<<<512, 256, 0, stream>>>(WV, WVt);
    wqk_kernel<<<512, 256, 0, stream>>>(WQ, WK, Mt_p);
    if (useHT)
        attn_kernel<true><<<2048, 256, 0, stream>>>(h_p, Mt_p, WVt, hT, out);
    else
        attn_kernel<false><<<2048, 256, 0, stream>>>(h_p, Mt_p, WVt, hT, out);
}